// Round 17
// baseline (206.396 us; speedup 1.0000x reference)
//
#include <hip/hip_runtime.h>

// Problem constants (fixed-shape problem)
constexpr int N_    = 8;
constexpr int M_    = 50000;
constexpr int FIN_  = 16;
constexpr int FOUT_ = 32;
constexpr int KCH_  = 4;
constexpr int NNZ_  = 800000;
constexpr int ROWB_ = 128;                  // bf16 elems per term row (256 B)
constexpr int SCAN_NB = (M_ + 255) / 256;   // 196 scan blocks
constexpr int RPB16_ = 16;                  // rows per spmm block (256 thr / 16)
constexpr int NBKT_  = (M_ + 255) / 256;    // 196 row-buckets (256 rows each)
constexpr int BSC_BLOCKS_ = 256;            // bucket-scatter blocks
constexpr int CHUNK_ = NNZ_ / BSC_BLOCKS_;  // 3125 nnz per block (exact)
constexpr int NTILE_ = M_ / 2;              // 25000 2-m tiles (exact)

// Term-row internal layout: element c = n*16 + f  (m-row is 256 B contiguous;
// spmm gathers whole rows so the internal order is free — chosen so both the
// MFMA A-fragment and k_accum read contiguous 16 B per (m,n,k)).

typedef float f32x4 __attribute__((ext_vector_type(4)));
typedef unsigned short u16x8 __attribute__((ext_vector_type(8)));
typedef short bf16x8 __attribute__((ext_vector_type(8)));   // MFMA A/B fragment
typedef float f32x4v __attribute__((ext_vector_type(4)));   // MFMA C/D fragment

__device__ __forceinline__ float bf2f(unsigned short u) {
    return __uint_as_float(((unsigned int)u) << 16);
}
__device__ __forceinline__ unsigned short f2bf(float f) {   // RNE
    unsigned int u = __float_as_uint(f);
    return (unsigned short)((u + 0x7fffu + ((u >> 16) & 1u)) >> 16);
}

// ---------------------------------------------------------------------------
// zero helper
__global__ void k_zero(int4* __restrict__ p, int n4) {
    int i = blockIdx.x * blockDim.x + threadIdx.x;
    if (i < n4) p[i] = make_int4(0, 0, 0, 0);
}

// ---------------------------------------------------------------------------
// X0 bf16: X0[m][n*16+f] = x[n][m][f]  (consecutive t -> consecutive x: coalesced)
__global__ void k_build_x0(const float* __restrict__ x, unsigned short* __restrict__ t0) {
    int t = blockIdx.x * blockDim.x + threadIdx.x;
    if (t >= M_ * ROWB_) return;
    int f = t & 15;
    int n = (t >> 4) & 7;
    int m = t >> 7;
    t0[t] = f2bf(x[((size_t)n * M_ + m) * FIN_ + f]);
}

// ---------------------------------------------------------------------------
// CSR row_ptr build (hist + hierarchical scan)
__global__ void k_hist(const int* __restrict__ row, int* __restrict__ cnt) {
    int i = blockIdx.x * blockDim.x + threadIdx.x;
    if (i < NNZ_) atomicAdd(&cnt[row[i]], 1);
}

__global__ void k_blocksum(const int* __restrict__ cnt, int* __restrict__ bsum) {
    __shared__ int s[256];
    int t = threadIdx.x;
    int idx = blockIdx.x * 256 + t;
    s[t] = (idx < M_) ? cnt[idx] : 0;
    __syncthreads();
    for (int off = 128; off > 0; off >>= 1) {
        if (t < off) s[t] += s[t + off];
        __syncthreads();
    }
    if (t == 0) bsum[blockIdx.x] = s[0];
}

__global__ void k_scan_bsum(const int* __restrict__ bsum, int* __restrict__ boff) {
    __shared__ int s[256];
    int t = threadIdx.x;
    int v = (t < SCAN_NB) ? bsum[t] : 0;
    s[t] = v;
    __syncthreads();
    for (int off = 1; off < 256; off <<= 1) {
        int a = (t >= off) ? s[t - off] : 0;
        __syncthreads();
        s[t] += a;
        __syncthreads();
    }
    if (t < SCAN_NB) boff[t] = s[t] - v;   // exclusive
}

__global__ void k_emit(const int* __restrict__ cnt, const int* __restrict__ boff,
                       int* __restrict__ row_ptr) {
    __shared__ int s[256];
    int t = threadIdx.x;
    int idx = blockIdx.x * 256 + t;
    int v = (idx < M_) ? cnt[idx] : 0;
    s[t] = v;
    __syncthreads();
    for (int off = 1; off < 256; off <<= 1) {
        int a = (t >= off) ? s[t - off] : 0;
        __syncthreads();
        s[t] += a;
        __syncthreads();
    }
    if (idx < M_) row_ptr[idx] = boff[blockIdx.x] + s[t] - v;
    if (idx == 0) row_ptr[M_] = NNZ_;
}

// bticket[b] = row_ptr[b*256] (bucket staging base = its CSR region base)
__global__ void k_binit(const int* __restrict__ row_ptr, int* __restrict__ bticket) {
    int b = blockIdx.x * blockDim.x + threadIdx.x;
    if (b < NBKT_) bticket[b] = row_ptr[b * 256];
}

// ---------------------------------------------------------------------------
// Phase 1: bucket scatter (one global atomic per (block,bucket); sequential
// per-bucket writes -> full-line write utilization).
__global__ __launch_bounds__(256) void k_bscatter(
        const float* __restrict__ vals, const int* __restrict__ row,
        const int* __restrict__ col, int* __restrict__ bticket,
        int2* __restrict__ stage) {
    __shared__ int cnt[NBKT_];
    __shared__ int base[NBKT_];
    const int t = threadIdx.x;
    const int i0 = blockIdx.x * CHUNK_;
    for (int b = t; b < NBKT_; b += 256) cnt[b] = 0;
    __syncthreads();
    for (int i = i0 + t; i < i0 + CHUNK_; i += 256)
        atomicAdd(&cnt[row[i] >> 8], 1);
    __syncthreads();
    for (int b = t; b < NBKT_; b += 256) {
        base[b] = (cnt[b] > 0) ? atomicAdd(&bticket[b], cnt[b]) : 0;
        cnt[b] = 0;
    }
    __syncthreads();
    for (int i = i0 + t; i < i0 + CHUNK_; i += 256) {
        const int r = row[i];
        const int b = r >> 8;
        const int k = atomicAdd(&cnt[b], 1);
        stage[base[b] + k] = make_int2(__float_as_int(vals[i]),
                                       col[i] | ((r & 255) << 16));
    }
}

// Phase 2: bucket-local CSR ordering.
__global__ __launch_bounds__(256) void k_bsort(
        const int* __restrict__ row_ptr, const int2* __restrict__ stage,
        int2* __restrict__ pairs) {
    __shared__ int rp_loc[257];
    __shared__ int c2[256];
    const int b  = blockIdx.x;
    const int t  = threadIdx.x;
    const int r0 = b * 256;
    const int nr = (r0 + 256 <= M_) ? 256 : (M_ - r0);
    if (t < nr) rp_loc[t] = row_ptr[r0 + t];
    if (t == 0) rp_loc[nr] = row_ptr[r0 + nr];   // boundary: ALWAYS loaded
    c2[t] = 0;
    __syncthreads();
    const int base = rp_loc[0];
    const int end  = rp_loc[nr];
    for (int e = base + t; e < end; e += 256) {
        const int2 en = stage[e];
        const int rl = en.y >> 16;
        const int k  = atomicAdd(&c2[rl], 1);
        pairs[rp_loc[rl] + k] = make_int2(en.x, en.y & 0xFFFF);
    }
}

// ---------------------------------------------------------------------------
// bf16 SpMM: Y[r,:] = scale * sum_j v_j * X[c_j,:]  (- prev[r,:] if prev)
// 16 lanes per row (16 B ushort8 per lane); j unrolled x4 with 4 independent
// accumulator chains -> 4 gathers in flight per lane (MLP x2 over R15).
__global__ __launch_bounds__(256) void k_spmm_bf16(
        const unsigned short* __restrict__ X, const unsigned short* __restrict__ prev,
        unsigned short* __restrict__ Y, const int* __restrict__ rp,
        const long long* __restrict__ pairs, float scale) {
    const int r = blockIdx.x * RPB16_ + (threadIdx.x >> 4);
    if (r >= M_) return;
    const int lane = threadIdx.x & 15;
    const unsigned short* Xl = X + lane * 8;
    const size_t off = (size_t)r * ROWB_ + lane * 8;

    const int jb = rp[r], je = rp[r + 1];
    f32x4 slo0 = {0,0,0,0}, shi0 = {0,0,0,0};
    f32x4 slo1 = {0,0,0,0}, shi1 = {0,0,0,0};
    f32x4 slo2 = {0,0,0,0}, shi2 = {0,0,0,0};
    f32x4 slo3 = {0,0,0,0}, shi3 = {0,0,0,0};
    int j = jb;
    for (; j + 3 < je; j += 4) {
        const long long p0 = pairs[j],     p1 = pairs[j + 1];
        const long long p2 = pairs[j + 2], p3 = pairs[j + 3];
        const float v0 = __int_as_float((int)p0);
        const float v1 = __int_as_float((int)p1);
        const float v2 = __int_as_float((int)p2);
        const float v3 = __int_as_float((int)p3);
        const u16x8 u0 = *reinterpret_cast<const u16x8*>(Xl + (size_t)((int)(p0 >> 32)) * ROWB_);
        const u16x8 u1 = *reinterpret_cast<const u16x8*>(Xl + (size_t)((int)(p1 >> 32)) * ROWB_);
        const u16x8 u2 = *reinterpret_cast<const u16x8*>(Xl + (size_t)((int)(p2 >> 32)) * ROWB_);
        const u16x8 u3 = *reinterpret_cast<const u16x8*>(Xl + (size_t)((int)(p3 >> 32)) * ROWB_);
        slo0 += v0 * (f32x4){bf2f(u0[0]), bf2f(u0[1]), bf2f(u0[2]), bf2f(u0[3])};
        shi0 += v0 * (f32x4){bf2f(u0[4]), bf2f(u0[5]), bf2f(u0[6]), bf2f(u0[7])};
        slo1 += v1 * (f32x4){bf2f(u1[0]), bf2f(u1[1]), bf2f(u1[2]), bf2f(u1[3])};
        shi1 += v1 * (f32x4){bf2f(u1[4]), bf2f(u1[5]), bf2f(u1[6]), bf2f(u1[7])};
        slo2 += v2 * (f32x4){bf2f(u2[0]), bf2f(u2[1]), bf2f(u2[2]), bf2f(u2[3])};
        shi2 += v2 * (f32x4){bf2f(u2[4]), bf2f(u2[5]), bf2f(u2[6]), bf2f(u2[7])};
        slo3 += v3 * (f32x4){bf2f(u3[0]), bf2f(u3[1]), bf2f(u3[2]), bf2f(u3[3])};
        shi3 += v3 * (f32x4){bf2f(u3[4]), bf2f(u3[5]), bf2f(u3[6]), bf2f(u3[7])};
    }
    for (; j < je; ++j) {
        const long long p0 = pairs[j];
        const float v0 = __int_as_float((int)p0);
        const u16x8 u0 = *reinterpret_cast<const u16x8*>(Xl + (size_t)((int)(p0 >> 32)) * ROWB_);
        slo0 += v0 * (f32x4){bf2f(u0[0]), bf2f(u0[1]), bf2f(u0[2]), bf2f(u0[3])};
        shi0 += v0 * (f32x4){bf2f(u0[4]), bf2f(u0[5]), bf2f(u0[6]), bf2f(u0[7])};
    }
    f32x4 rlo = scale * ((slo0 + slo1) + (slo2 + slo3));
    f32x4 rhi = scale * ((shi0 + shi1) + (shi2 + shi3));
    if (prev) {
        const u16x8 pv = *reinterpret_cast<const u16x8*>(prev + off);
        rlo -= (f32x4){bf2f(pv[0]), bf2f(pv[1]), bf2f(pv[2]), bf2f(pv[3])};
        rhi -= (f32x4){bf2f(pv[4]), bf2f(pv[5]), bf2f(pv[6]), bf2f(pv[7])};
    }
    u16x8 o;
    o[0] = f2bf(rlo.x); o[1] = f2bf(rlo.y); o[2] = f2bf(rlo.z); o[3] = f2bf(rlo.w);
    o[4] = f2bf(rhi.x); o[5] = f2bf(rhi.y); o[6] = f2bf(rhi.z); o[7] = f2bf(rhi.w);
    *reinterpret_cast<u16x8*>(Y + off) = o;
}

// ---------------------------------------------------------------------------
// MFMA final einsum. Per 2-m tile: out[16 rows = 2m x 8n][32 o] =
//   sum_{K=64 (f,kcheb)} A[row][K] * B[K][o] + bias,
// as 2 chained mfma_f32_16x16x32_bf16 per o-half (K split 0..31 -> T0/T1,
// 32..63 -> T2/T3). A-frag: lane l&15 = row (mloc = (l&15)>>3, n = l&7),
// K-group (l>>4)*8+j -> one contiguous 16 B term load. B-frag: w bf16 held in
// 16 VGPRs for the whole kernel (consistent K labels A<->B make the result
// invariant to the HW's internal K permutation). C/D: col=l&15,
// row=(l>>4)*4+reg [verified mapping]. Bias folded into acc init. No LDS.
__global__ __launch_bounds__(256) void k_final(
        const unsigned short* __restrict__ T0, const unsigned short* __restrict__ T1,
        const unsigned short* __restrict__ T2, const unsigned short* __restrict__ T3,
        const float* __restrict__ w, const float* __restrict__ b,
        float* __restrict__ out) {
    const int lane = threadIdx.x & 63;
    const int lg   = lane >> 4;          // 0..3 (K-group / D-row group)
    const int ll   = lane & 15;          // A row / B col / D col
    const int wid    = (blockIdx.x * blockDim.x + threadIdx.x) >> 6;
    const int nwaves = (gridDim.x * blockDim.x) >> 6;

    // B fragments: mm = which MFMA (0: kcheb 0/1, 1: kcheb 2/3), oh = o-half.
    bf16x8 bfrag[2][2];
#pragma unroll
    for (int mm = 0; mm < 2; ++mm)
#pragma unroll
        for (int oh = 0; oh < 2; ++oh)
#pragma unroll
            for (int j = 0; j < 8; ++j) {
                const int k  = lg * 8 + j;            // 0..31
                const int kc = mm * 2 + (k >> 4);     // cheb index
                const int f  = k & 15;
                bfrag[mm][oh][j] =
                    (short)f2bf(w[(f * KCH_ + kc) * FOUT_ + oh * 16 + ll]);
            }
    const float bias0 = b[ll], bias1 = b[16 + ll];

    // A-source: MFMA0 reads T0 (lg 0,1) / T1 (lg 2,3); MFMA1 reads T2/T3.
    const unsigned short* TA = (lg < 2) ? T0 : T1;
    const unsigned short* TB = (lg < 2) ? T2 : T3;
    const int mloc = ll >> 3;
    const int n    = ll & 7;
    const int fofs = (lg & 1) * 8;
    const size_t eoff = (size_t)n * 16 + fofs;

    for (int tile = wid; tile < NTILE_; tile += nwaves) {
        const int m0 = tile * 2;
        const size_t rowoff = (size_t)(m0 + mloc) * ROWB_ + eoff;
        const bf16x8 a01 = *reinterpret_cast<const bf16x8*>(TA + rowoff);
        const bf16x8 a23 = *reinterpret_cast<const bf16x8*>(TB + rowoff);

        f32x4v acc0 = {bias0, bias0, bias0, bias0};
        f32x4v acc1 = {bias1, bias1, bias1, bias1};
        acc0 = __builtin_amdgcn_mfma_f32_16x16x32_bf16(a01, bfrag[0][0], acc0, 0, 0, 0);
        acc0 = __builtin_amdgcn_mfma_f32_16x16x32_bf16(a23, bfrag[1][0], acc0, 0, 0, 0);
        acc1 = __builtin_amdgcn_mfma_f32_16x16x32_bf16(a01, bfrag[0][1], acc1, 0, 0, 0);
        acc1 = __builtin_amdgcn_mfma_f32_16x16x32_bf16(a23, bfrag[1][1], acc1, 0, 0, 0);

#pragma unroll
        for (int r = 0; r < 4; ++r) {
            const int drow = lg * 4 + r;              // 0..15
            const int dm   = drow >> 3;
            const int dn   = drow & 7;
            float* base = out + ((size_t)dn * M_ + m0 + dm) * FOUT_;
            base[ll]      = acc0[r];
            base[16 + ll] = acc1[r];
        }
    }
}

// ---------------------------------------------------------------------------
// fallback per-term accumulation (bf16 term, [m][n*16+f] layout)
__global__ __launch_bounds__(256) void k_accum(
        const unsigned short* __restrict__ T, const float* __restrict__ w,
        const float* __restrict__ b, float* __restrict__ out, int k, int init) {
    int t = blockIdx.x * blockDim.x + threadIdx.x;
    if (t >= M_ * N_) return;
    const int n = t & 7;
    const int m = t >> 3;

    float* base = out + ((size_t)n * M_ + m) * FOUT_;
    float4 acc[8];
#pragma unroll
    for (int o4 = 0; o4 < 8; ++o4)
        acc[o4] = init ? *reinterpret_cast<const float4*>(b + o4 * 4)
                       : *reinterpret_cast<const float4*>(base + o4 * 4);

    const unsigned short* tk = T + (size_t)m * ROWB_ + n * 16;
    const u16x8 lo = *reinterpret_cast<const u16x8*>(tk);
    const u16x8 hi = *reinterpret_cast<const u16x8*>(tk + 8);
#pragma unroll
    for (int f = 0; f < FIN_; ++f) {
        const float tv = bf2f(f < 8 ? lo[f] : hi[f - 8]);
        const float* wr = w + (f * KCH_ + k) * FOUT_;
#pragma unroll
        for (int o4 = 0; o4 < 8; ++o4) {
            float4 wv = *reinterpret_cast<const float4*>(wr + o4 * 4);
            acc[o4].x += tv * wv.x; acc[o4].y += tv * wv.y;
            acc[o4].z += tv * wv.z; acc[o4].w += tv * wv.w;
        }
    }
#pragma unroll
    for (int o4 = 0; o4 < 8; ++o4)
        *reinterpret_cast<float4*>(base + o4 * 4) = acc[o4];
}

// ---------------------------------------------------------------------------
extern "C" void kernel_launch(void* const* d_in, const int* in_sizes, int n_in,
                              void* d_out, int out_size, void* d_ws, size_t ws_size,
                              hipStream_t stream) {
    const float* x    = (const float*)d_in[0];
    const float* vals = (const float*)d_in[1];
    const float* w    = (const float*)d_in[2];
    const float* b    = (const float*)d_in[3];
    const int*   row  = (const int*)d_in[4];
    const int*   col  = (const int*)d_in[5];
    float* out = (float*)d_out;

    const size_t tElems = (size_t)M_ * ROWB_;             // 6.4M bf16 per term
    const size_t tBytes = tElems * 2;                     // 12.8 MB
    const size_t csrBytes = (size_t)(M_ + 1) * 4 + (size_t)M_ * 4
                          + 2 * (size_t)NNZ_ * 8 + 4096;  // pairs + stage
    const size_t fusedBytes = 4 * tBytes + csrBytes;      // ~71 MB
    const bool fused = ws_size >= fusedBytes;

    unsigned short* X0 = (unsigned short*)d_ws;
    unsigned short* T1 = X0 + tElems;
    unsigned short* T2 = T1 + tElems;
    unsigned short* T3 = fused ? (T2 + tElems) : T1;      // fallback: in-place
    char* p = (char*)(fused ? (T3 + tElems) : (T2 + tElems));
    int2* pairs   = (int2*)p;              p += (size_t)NNZ_ * 8;
    int2* stage   = (int2*)p;              p += (size_t)NNZ_ * 8;
    int*  row_ptr = (int*)p;               p += (size_t)(M_ + 1) * 4;
    int*  cnt     = (int*)p;               p += (size_t)M_ * 4;
    int*  bsum    = (int*)p;               p += 1024;
    int*  boff    = (int*)p;               p += 1024;
    int*  bticket = (int*)p;

    const int TB = 256;
    dim3 blk(TB);
    dim3 gN((NNZ_ + TB - 1) / TB);                 // per-nnz
    dim3 gX((M_ * ROWB_ + TB - 1) / TB);           // build_x0
    dim3 gS((M_ + RPB16_ - 1) / RPB16_);           // spmm: 16 rows per block
    dim3 gFM(1024);                                // MFMA final: grid-stride waves
    dim3 gF((M_ * N_ + TB - 1) / TB);              // fallback k_accum
    dim3 gZ((M_ / 4 + TB - 1) / TB);               // k_zero (M_ % 4 == 0)

    // ---- build CSR row_ptr ----
    hipLaunchKernelGGL(k_zero,      gZ, blk, 0, stream, (int4*)cnt, M_ / 4);
    hipLaunchKernelGGL(k_hist,      gN, blk, 0, stream, row, cnt);
    hipLaunchKernelGGL(k_blocksum,  dim3(SCAN_NB), blk, 0, stream, cnt, bsum);
    hipLaunchKernelGGL(k_scan_bsum, dim3(1), blk, 0, stream, bsum, boff);
    hipLaunchKernelGGL(k_emit,      dim3(SCAN_NB), blk, 0, stream, cnt, boff, row_ptr);

    // ---- two-phase bucketed scatter ----
    hipLaunchKernelGGL(k_binit,    dim3(1), blk, 0, stream, row_ptr, bticket);
    hipLaunchKernelGGL(k_bscatter, dim3(BSC_BLOCKS_), blk, 0, stream,
                       vals, row, col, bticket, stage);
    hipLaunchKernelGGL(k_bsort,    dim3(NBKT_), blk, 0, stream, row_ptr, stage, pairs);

    // ---- X0 (bf16) ----
    hipLaunchKernelGGL(k_build_x0, gX, blk, 0, stream, x, X0);

    const long long* pr = (const long long*)pairs;
    if (fused) {
        hipLaunchKernelGGL(k_spmm_bf16, gS, blk, 0, stream, X0, (const unsigned short*)nullptr,
                           T1, row_ptr, pr, 1.0f);
        hipLaunchKernelGGL(k_spmm_bf16, gS, blk, 0, stream, T1, X0, T2, row_ptr, pr, 2.0f);
        hipLaunchKernelGGL(k_spmm_bf16, gS, blk, 0, stream, T2, T1, T3, row_ptr, pr, 2.0f);
        hipLaunchKernelGGL(k_final, gFM, blk, 0, stream, X0, T1, T2, T3, w, b, out);
    } else {
        hipLaunchKernelGGL(k_accum, gF, blk, 0, stream, X0, w, b, out, 0, 1);
        hipLaunchKernelGGL(k_spmm_bf16, gS, blk, 0, stream, X0, (const unsigned short*)nullptr,
                           T1, row_ptr, pr, 1.0f);
        hipLaunchKernelGGL(k_accum, gF, blk, 0, stream, T1, w, b, out, 1, 0);
        hipLaunchKernelGGL(k_spmm_bf16, gS, blk, 0, stream, T1, X0, T2, row_ptr, pr, 2.0f);
        hipLaunchKernelGGL(k_accum, gF, blk, 0, stream, T2, w, b, out, 2, 0);
        // T3 overwrites T1 in place: same-thread read-then-write, no hazard.
        hipLaunchKernelGGL(k_spmm_bf16, gS, blk, 0, stream, T2, T1, T1, row_ptr, pr, 2.0f);
        hipLaunchKernelGGL(k_accum, gF, blk, 0, stream, T1, w, b, out, 3, 0);
    }
}

// Round 18
// 175.377 us; speedup vs baseline: 1.1769x; 1.1769x over previous
//
#include <hip/hip_runtime.h>

// Problem constants (fixed-shape problem)
constexpr int N_    = 8;
constexpr int M_    = 50000;
constexpr int FIN_  = 16;
constexpr int FOUT_ = 32;
constexpr int KCH_  = 4;
constexpr int NNZ_  = 800000;
constexpr int ROWB_ = 128;                  // bf16 elems per term row (256 B)
constexpr int RPB16_ = 16;                  // rows per spmm block (256 thr / 16)
constexpr int NBKT_  = (M_ + 255) / 256;    // 196 row-buckets (256 rows each)
constexpr int BSC_BLOCKS_ = 256;            // bucket-scatter blocks
constexpr int CHUNK_ = NNZ_ / BSC_BLOCKS_;  // 3125 nnz per block (exact)
constexpr int NTILE_ = M_ / 2;              // 25000 2-m tiles (exact)

// Term-row internal layout: element c = n*16 + f  (m-row is 256 B contiguous;
// spmm gathers whole rows so the internal order is free — chosen so both the
// MFMA A-fragment and k_accum read contiguous 16 B per (m,n,k)).

typedef float f32x4 __attribute__((ext_vector_type(4)));
typedef unsigned short u16x8 __attribute__((ext_vector_type(8)));
typedef short bf16x8 __attribute__((ext_vector_type(8)));   // MFMA A/B fragment
typedef float f32x4v __attribute__((ext_vector_type(4)));   // MFMA C/D fragment

__device__ __forceinline__ float bf2f(unsigned short u) {
    return __uint_as_float(((unsigned int)u) << 16);
}
__device__ __forceinline__ unsigned short f2bf(float f) {   // RNE
    unsigned int u = __float_as_uint(f);
    return (unsigned short)((u + 0x7fffu + ((u >> 16) & 1u)) >> 16);
}

// ---------------------------------------------------------------------------
// tiny zero (196 bucket counters)
__global__ void k_zero_small(int* __restrict__ p, int n) {
    int i = blockIdx.x * blockDim.x + threadIdx.x;
    if (i < n) p[i] = 0;
}

// ---------------------------------------------------------------------------
// X0 bf16: X0[m][n*16+f] = x[n][m][f]  (consecutive t -> consecutive x: coalesced)
__global__ void k_build_x0(const float* __restrict__ x, unsigned short* __restrict__ t0) {
    int t = blockIdx.x * blockDim.x + threadIdx.x;
    if (t >= M_ * ROWB_) return;
    int f = t & 15;
    int n = (t >> 4) & 7;
    int m = t >> 7;
    t0[t] = f2bf(x[((size_t)n * M_ + m) * FIN_ + f]);
}

// ---------------------------------------------------------------------------
// Bucket-level CSR build (no M-sized histogram / scan):
// k_bhist: LDS-reduced bucket histogram (50k global atomics on 196 ints).
__global__ __launch_bounds__(256) void k_bhist(const int* __restrict__ row,
                                               int* __restrict__ bcnt) {
    __shared__ int cnt[NBKT_];
    const int t = threadIdx.x;
    for (int b = t; b < NBKT_; b += 256) cnt[b] = 0;
    __syncthreads();
    const int i0 = blockIdx.x * CHUNK_;
    for (int i = i0 + t; i < i0 + CHUNK_; i += 256)
        atomicAdd(&cnt[row[i] >> 8], 1);
    __syncthreads();
    for (int b = t; b < NBKT_; b += 256)
        if (cnt[b]) atomicAdd(&bcnt[b], cnt[b]);
}

// k_bscan: 1-block exclusive scan of 196 bucket counts -> bbase/bticket.
__global__ void k_bscan(const int* __restrict__ bcnt, int* __restrict__ bbase,
                        int* __restrict__ bticket, int* __restrict__ row_ptr) {
    __shared__ int s[256];
    const int t = threadIdx.x;
    const int v = (t < NBKT_) ? bcnt[t] : 0;
    s[t] = v;
    __syncthreads();
    for (int off = 1; off < 256; off <<= 1) {
        int a = (t >= off) ? s[t - off] : 0;
        __syncthreads();
        s[t] += a;
        __syncthreads();
    }
    if (t < NBKT_) {
        const int e = s[t] - v;   // exclusive
        bbase[t]   = e;
        bticket[t] = e;
    }
    if (t == 0) { bbase[NBKT_] = NNZ_; row_ptr[M_] = NNZ_; }
}

// Phase 1: bucket scatter (one global atomic per (block,bucket); sequential
// per-bucket writes -> full-line write utilization).
__global__ __launch_bounds__(256) void k_bscatter(
        const float* __restrict__ vals, const int* __restrict__ row,
        const int* __restrict__ col, int* __restrict__ bticket,
        int2* __restrict__ stage) {
    __shared__ int cnt[NBKT_];
    __shared__ int base[NBKT_];
    const int t = threadIdx.x;
    const int i0 = blockIdx.x * CHUNK_;
    for (int b = t; b < NBKT_; b += 256) cnt[b] = 0;
    __syncthreads();
    for (int i = i0 + t; i < i0 + CHUNK_; i += 256)
        atomicAdd(&cnt[row[i] >> 8], 1);
    __syncthreads();
    for (int b = t; b < NBKT_; b += 256) {
        base[b] = (cnt[b] > 0) ? atomicAdd(&bticket[b], cnt[b]) : 0;
        cnt[b] = 0;
    }
    __syncthreads();
    for (int i = i0 + t; i < i0 + CHUNK_; i += 256) {
        const int r = row[i];
        const int b = r >> 8;
        const int k = atomicAdd(&cnt[b], 1);
        stage[base[b] + k] = make_int2(__float_as_int(vals[i]),
                                       col[i] | ((r & 255) << 16));
    }
}

// Phase 2: bucket-local CSR ordering + row_ptr emission (per-bucket LDS
// count + local scan; all reads/writes confined to the bucket region).
__global__ __launch_bounds__(256) void k_bsort(
        const int* __restrict__ bbase, const int2* __restrict__ stage,
        int2* __restrict__ pairs, int* __restrict__ row_ptr) {
    __shared__ int c2[256];
    __shared__ int s[256];
    __shared__ int rloc[256];
    const int b  = blockIdx.x;
    const int t  = threadIdx.x;
    const int r0 = b * 256;
    const int nr = (r0 + 256 <= M_) ? 256 : (M_ - r0);
    const int base = bbase[b];
    const int end  = bbase[b + 1];
    c2[t] = 0;
    __syncthreads();
    for (int e = base + t; e < end; e += 256)
        atomicAdd(&c2[stage[e].y >> 16], 1);
    __syncthreads();
    const int v = c2[t];
    s[t] = v;
    __syncthreads();
    for (int off = 1; off < 256; off <<= 1) {
        int a = (t >= off) ? s[t - off] : 0;
        __syncthreads();
        s[t] += a;
        __syncthreads();
    }
    rloc[t] = base + s[t] - v;        // exclusive row start within bucket
    if (t < nr) row_ptr[r0 + t] = rloc[t];
    c2[t] = 0;
    __syncthreads();
    for (int e = base + t; e < end; e += 256) {
        const int2 en = stage[e];
        const int rl = en.y >> 16;
        const int k  = atomicAdd(&c2[rl], 1);
        pairs[rloc[rl] + k] = make_int2(en.x, en.y & 0xFFFF);
    }
}

// ---------------------------------------------------------------------------
// bf16 SpMM: Y[r,:] = scale * sum_j v_j * X[c_j,:]  (- prev[r,:] if prev)
// 16 lanes per row (16 B ushort8 per lane); j unrolled x4 with 4 independent
// accumulator chains (LLC-service-saturated per R15/R16 A/B).
__global__ __launch_bounds__(256) void k_spmm_bf16(
        const unsigned short* __restrict__ X, const unsigned short* __restrict__ prev,
        unsigned short* __restrict__ Y, const int* __restrict__ rp,
        const long long* __restrict__ pairs, float scale) {
    const int r = blockIdx.x * RPB16_ + (threadIdx.x >> 4);
    if (r >= M_) return;
    const int lane = threadIdx.x & 15;
    const unsigned short* Xl = X + lane * 8;
    const size_t off = (size_t)r * ROWB_ + lane * 8;

    const int jb = rp[r], je = rp[r + 1];
    f32x4 slo0 = {0,0,0,0}, shi0 = {0,0,0,0};
    f32x4 slo1 = {0,0,0,0}, shi1 = {0,0,0,0};
    f32x4 slo2 = {0,0,0,0}, shi2 = {0,0,0,0};
    f32x4 slo3 = {0,0,0,0}, shi3 = {0,0,0,0};
    int j = jb;
    for (; j + 3 < je; j += 4) {
        const long long p0 = pairs[j],     p1 = pairs[j + 1];
        const long long p2 = pairs[j + 2], p3 = pairs[j + 3];
        const float v0 = __int_as_float((int)p0);
        const float v1 = __int_as_float((int)p1);
        const float v2 = __int_as_float((int)p2);
        const float v3 = __int_as_float((int)p3);
        const u16x8 u0 = *reinterpret_cast<const u16x8*>(Xl + (size_t)((int)(p0 >> 32)) * ROWB_);
        const u16x8 u1 = *reinterpret_cast<const u16x8*>(Xl + (size_t)((int)(p1 >> 32)) * ROWB_);
        const u16x8 u2 = *reinterpret_cast<const u16x8*>(Xl + (size_t)((int)(p2 >> 32)) * ROWB_);
        const u16x8 u3 = *reinterpret_cast<const u16x8*>(Xl + (size_t)((int)(p3 >> 32)) * ROWB_);
        slo0 += v0 * (f32x4){bf2f(u0[0]), bf2f(u0[1]), bf2f(u0[2]), bf2f(u0[3])};
        shi0 += v0 * (f32x4){bf2f(u0[4]), bf2f(u0[5]), bf2f(u0[6]), bf2f(u0[7])};
        slo1 += v1 * (f32x4){bf2f(u1[0]), bf2f(u1[1]), bf2f(u1[2]), bf2f(u1[3])};
        shi1 += v1 * (f32x4){bf2f(u1[4]), bf2f(u1[5]), bf2f(u1[6]), bf2f(u1[7])};
        slo2 += v2 * (f32x4){bf2f(u2[0]), bf2f(u2[1]), bf2f(u2[2]), bf2f(u2[3])};
        shi2 += v2 * (f32x4){bf2f(u2[4]), bf2f(u2[5]), bf2f(u2[6]), bf2f(u2[7])};
        slo3 += v3 * (f32x4){bf2f(u3[0]), bf2f(u3[1]), bf2f(u3[2]), bf2f(u3[3])};
        shi3 += v3 * (f32x4){bf2f(u3[4]), bf2f(u3[5]), bf2f(u3[6]), bf2f(u3[7])};
    }
    for (; j < je; ++j) {
        const long long p0 = pairs[j];
        const float v0 = __int_as_float((int)p0);
        const u16x8 u0 = *reinterpret_cast<const u16x8*>(Xl + (size_t)((int)(p0 >> 32)) * ROWB_);
        slo0 += v0 * (f32x4){bf2f(u0[0]), bf2f(u0[1]), bf2f(u0[2]), bf2f(u0[3])};
        shi0 += v0 * (f32x4){bf2f(u0[4]), bf2f(u0[5]), bf2f(u0[6]), bf2f(u0[7])};
    }
    f32x4 rlo = scale * ((slo0 + slo1) + (slo2 + slo3));
    f32x4 rhi = scale * ((shi0 + shi1) + (shi2 + shi3));
    if (prev) {
        const u16x8 pv = *reinterpret_cast<const u16x8*>(prev + off);
        rlo -= (f32x4){bf2f(pv[0]), bf2f(pv[1]), bf2f(pv[2]), bf2f(pv[3])};
        rhi -= (f32x4){bf2f(pv[4]), bf2f(pv[5]), bf2f(pv[6]), bf2f(pv[7])};
    }
    u16x8 o;
    o[0] = f2bf(rlo.x); o[1] = f2bf(rlo.y); o[2] = f2bf(rlo.z); o[3] = f2bf(rlo.w);
    o[4] = f2bf(rhi.x); o[5] = f2bf(rhi.y); o[6] = f2bf(rhi.z); o[7] = f2bf(rhi.w);
    *reinterpret_cast<u16x8*>(Y + off) = o;
}

// ---------------------------------------------------------------------------
// MFMA final einsum. Per 2-m tile: out[16 rows = 2m x 8n][32 o] =
//   sum_{K=64 (f,kcheb)} A[row][K] * B[K][o] + bias,
// as 2 chained mfma_f32_16x16x32_bf16 per o-half (K split 0..31 -> T0/T1,
// 32..63 -> T2/T3). B-frag: w bf16 held in 16 VGPRs for the whole kernel.
// C/D: col=l&15, row=(l>>4)*4+reg [verified mapping]. Bias in acc init.
__global__ __launch_bounds__(256) void k_final(
        const unsigned short* __restrict__ T0, const unsigned short* __restrict__ T1,
        const unsigned short* __restrict__ T2, const unsigned short* __restrict__ T3,
        const float* __restrict__ w, const float* __restrict__ b,
        float* __restrict__ out) {
    const int lane = threadIdx.x & 63;
    const int lg   = lane >> 4;          // 0..3 (K-group / D-row group)
    const int ll   = lane & 15;          // A row / B col / D col
    const int wid    = (blockIdx.x * blockDim.x + threadIdx.x) >> 6;
    const int nwaves = (gridDim.x * blockDim.x) >> 6;

    bf16x8 bfrag[2][2];
#pragma unroll
    for (int mm = 0; mm < 2; ++mm)
#pragma unroll
        for (int oh = 0; oh < 2; ++oh)
#pragma unroll
            for (int j = 0; j < 8; ++j) {
                const int k  = lg * 8 + j;            // 0..31
                const int kc = mm * 2 + (k >> 4);     // cheb index
                const int f  = k & 15;
                bfrag[mm][oh][j] =
                    (short)f2bf(w[(f * KCH_ + kc) * FOUT_ + oh * 16 + ll]);
            }
    const float bias0 = b[ll], bias1 = b[16 + ll];

    const unsigned short* TA = (lg < 2) ? T0 : T1;
    const unsigned short* TB = (lg < 2) ? T2 : T3;
    const int mloc = ll >> 3;
    const int n    = ll & 7;
    const int fofs = (lg & 1) * 8;
    const size_t eoff = (size_t)n * 16 + fofs;

    for (int tile = wid; tile < NTILE_; tile += nwaves) {
        const int m0 = tile * 2;
        const size_t rowoff = (size_t)(m0 + mloc) * ROWB_ + eoff;
        const bf16x8 a01 = *reinterpret_cast<const bf16x8*>(TA + rowoff);
        const bf16x8 a23 = *reinterpret_cast<const bf16x8*>(TB + rowoff);

        f32x4v acc0 = {bias0, bias0, bias0, bias0};
        f32x4v acc1 = {bias1, bias1, bias1, bias1};
        acc0 = __builtin_amdgcn_mfma_f32_16x16x32_bf16(a01, bfrag[0][0], acc0, 0, 0, 0);
        acc0 = __builtin_amdgcn_mfma_f32_16x16x32_bf16(a23, bfrag[1][0], acc0, 0, 0, 0);
        acc1 = __builtin_amdgcn_mfma_f32_16x16x32_bf16(a01, bfrag[0][1], acc1, 0, 0, 0);
        acc1 = __builtin_amdgcn_mfma_f32_16x16x32_bf16(a23, bfrag[1][1], acc1, 0, 0, 0);

#pragma unroll
        for (int r = 0; r < 4; ++r) {
            const int drow = lg * 4 + r;              // 0..15
            const int dm   = drow >> 3;
            const int dn   = drow & 7;
            float* base = out + ((size_t)dn * M_ + m0 + dm) * FOUT_;
            base[ll]      = acc0[r];
            base[16 + ll] = acc1[r];
        }
    }
}

// ---------------------------------------------------------------------------
// fallback per-term accumulation (bf16 term, [m][n*16+f] layout)
__global__ __launch_bounds__(256) void k_accum(
        const unsigned short* __restrict__ T, const float* __restrict__ w,
        const float* __restrict__ b, float* __restrict__ out, int k, int init) {
    int t = blockIdx.x * blockDim.x + threadIdx.x;
    if (t >= M_ * N_) return;
    const int n = t & 7;
    const int m = t >> 3;

    float* base = out + ((size_t)n * M_ + m) * FOUT_;
    float4 acc[8];
#pragma unroll
    for (int o4 = 0; o4 < 8; ++o4)
        acc[o4] = init ? *reinterpret_cast<const float4*>(b + o4 * 4)
                       : *reinterpret_cast<const float4*>(base + o4 * 4);

    const unsigned short* tk = T + (size_t)m * ROWB_ + n * 16;
    const u16x8 lo = *reinterpret_cast<const u16x8*>(tk);
    const u16x8 hi = *reinterpret_cast<const u16x8*>(tk + 8);
#pragma unroll
    for (int f = 0; f < FIN_; ++f) {
        const float tv = bf2f(f < 8 ? lo[f] : hi[f - 8]);
        const float* wr = w + (f * KCH_ + k) * FOUT_;
#pragma unroll
        for (int o4 = 0; o4 < 8; ++o4) {
            float4 wv = *reinterpret_cast<const float4*>(wr + o4 * 4);
            acc[o4].x += tv * wv.x; acc[o4].y += tv * wv.y;
            acc[o4].z += tv * wv.z; acc[o4].w += tv * wv.w;
        }
    }
#pragma unroll
    for (int o4 = 0; o4 < 8; ++o4)
        *reinterpret_cast<float4*>(base + o4 * 4) = acc[o4];
}

// ---------------------------------------------------------------------------
extern "C" void kernel_launch(void* const* d_in, const int* in_sizes, int n_in,
                              void* d_out, int out_size, void* d_ws, size_t ws_size,
                              hipStream_t stream) {
    const float* x    = (const float*)d_in[0];
    const float* vals = (const float*)d_in[1];
    const float* w    = (const float*)d_in[2];
    const float* b    = (const float*)d_in[3];
    const int*   row  = (const int*)d_in[4];
    const int*   col  = (const int*)d_in[5];
    float* out = (float*)d_out;

    const size_t tElems = (size_t)M_ * ROWB_;             // 6.4M bf16 per term
    const size_t tBytes = tElems * 2;                     // 12.8 MB
    const size_t csrBytes = (size_t)(M_ + 1) * 4
                          + 2 * (size_t)NNZ_ * 8 + 8192;  // pairs + stage + small
    const size_t fusedBytes = 4 * tBytes + csrBytes;      // ~64 MB
    const bool fused = ws_size >= fusedBytes;

    unsigned short* X0 = (unsigned short*)d_ws;
    unsigned short* T1 = X0 + tElems;
    unsigned short* T2 = T1 + tElems;
    unsigned short* T3 = fused ? (T2 + tElems) : T1;      // fallback: in-place
    char* p = (char*)(fused ? (T3 + tElems) : (T2 + tElems));
    int2* pairs   = (int2*)p;              p += (size_t)NNZ_ * 8;
    int2* stage   = (int2*)p;              p += (size_t)NNZ_ * 8;
    int*  row_ptr = (int*)p;               p += (size_t)(M_ + 1) * 4;
    int*  bcnt    = (int*)p;               p += 1024;
    int*  bbase   = (int*)p;               p += 1024;     // NBKT_+1 ints
    int*  bticket = (int*)p;

    const int TB = 256;
    dim3 blk(TB);
    dim3 gX((M_ * ROWB_ + TB - 1) / TB);           // build_x0
    dim3 gS((M_ + RPB16_ - 1) / RPB16_);           // spmm: 16 rows per block
    dim3 gFM(1024);                                // MFMA final: grid-stride waves
    dim3 gF((M_ * N_ + TB - 1) / TB);              // fallback k_accum

    // ---- bucket-level CSR build (no M-sized histogram/scan) ----
    hipLaunchKernelGGL(k_zero_small, dim3(1), blk, 0, stream, bcnt, NBKT_);
    hipLaunchKernelGGL(k_bhist,    dim3(BSC_BLOCKS_), blk, 0, stream, row, bcnt);
    hipLaunchKernelGGL(k_bscan,    dim3(1), blk, 0, stream, bcnt, bbase, bticket, row_ptr);
    hipLaunchKernelGGL(k_bscatter, dim3(BSC_BLOCKS_), blk, 0, stream,
                       vals, row, col, bticket, stage);
    hipLaunchKernelGGL(k_bsort,    dim3(NBKT_), blk, 0, stream, bbase, stage,
                       pairs, row_ptr);

    // ---- X0 (bf16) ----
    hipLaunchKernelGGL(k_build_x0, gX, blk, 0, stream, x, X0);

    const long long* pr = (const long long*)pairs;
    if (fused) {
        hipLaunchKernelGGL(k_spmm_bf16, gS, blk, 0, stream, X0, (const unsigned short*)nullptr,
                           T1, row_ptr, pr, 1.0f);
        hipLaunchKernelGGL(k_spmm_bf16, gS, blk, 0, stream, T1, X0, T2, row_ptr, pr, 2.0f);
        hipLaunchKernelGGL(k_spmm_bf16, gS, blk, 0, stream, T2, T1, T3, row_ptr, pr, 2.0f);
        hipLaunchKernelGGL(k_final, gFM, blk, 0, stream, X0, T1, T2, T3, w, b, out);
    } else {
        hipLaunchKernelGGL(k_accum, gF, blk, 0, stream, X0, w, b, out, 0, 1);
        hipLaunchKernelGGL(k_spmm_bf16, gS, blk, 0, stream, X0, (const unsigned short*)nullptr,
                           T1, row_ptr, pr, 1.0f);
        hipLaunchKernelGGL(k_accum, gF, blk, 0, stream, T1, w, b, out, 1, 0);
        hipLaunchKernelGGL(k_spmm_bf16, gS, blk, 0, stream, T1, X0, T2, row_ptr, pr, 2.0f);
        hipLaunchKernelGGL(k_accum, gF, blk, 0, stream, T2, w, b, out, 2, 0);
        // T3 overwrites T1 in place: same-thread read-then-write, no hazard.
        hipLaunchKernelGGL(k_spmm_bf16, gS, blk, 0, stream, T2, T1, T1, row_ptr, pr, 2.0f);
        hipLaunchKernelGGL(k_accum, gF, blk, 0, stream, T1, w, b, out, 3, 0);
    }
}